// Round 11
// baseline (693.291 us; speedup 1.0000x reference)
//
#include <hip/hip_runtime.h>
#include <hip/hip_bf16.h>

typedef __bf16 bf16_t;
typedef __bf16 bf16x2 __attribute__((ext_vector_type(2)));
typedef __bf16 bf16x4 __attribute__((ext_vector_type(4)));
typedef __bf16 bf16x8 __attribute__((ext_vector_type(8)));
typedef float f32x4 __attribute__((ext_vector_type(4)));

#define DIM     1024
#define NEXP    8
#define VOCAB   16384
#define HIDDEN  2730
#define UPOUT   5460
#define NTOK    2048
#define NSLOT   4096
#define HRAW_LD 5472
#define H1_LD   2752
#define BM      256
#define MAXTILES 24

// ws layout (offsets in bytes) — verified slack (R8)
#define WS_COUNTS      0
#define WS_NTILES      64
#define WS_TILE_E      128
#define WS_TILE_M0     256
#define WS_TILE_MEND   384
#define WS_SLOT_IDS    1024
#define WS_SLOT_W      20480
#define WS_SLOT_OF_POS 40960
#define WS_POS_OF_SLOT 61440
#define WS_XSORTED     131072
#define WS_H2          8519680
#define WS_H1          16908288
#define WS_HRAW        39452672
#define WS_LOGITS      16908288ull /* overlays h1+h_raw (dead by proj time) */
#define WS_NEED_BIG    (WS_LOGITS + (size_t)NSLOT * VOCAB * 2)

__device__ __forceinline__ void gload_lds16(const void* g, void* l) {
    __builtin_amdgcn_global_load_lds((const __attribute__((address_space(1))) void*)g,
                                     (__attribute__((address_space(3))) void*)l, 16, 0, 0);
}
__device__ __forceinline__ int swzm(int r) { return (r ^ (r >> 2)) & 3; }

// ---------------- router ----------------
__global__ __launch_bounds__(256) void router_kernel(const float* __restrict__ x,
        const float* __restrict__ wr, int* __restrict__ slot_ids,
        float* __restrict__ slot_w, int* __restrict__ counts) {
    const int lane = threadIdx.x & 63;
    const int wave = threadIdx.x >> 6;
    const int token = blockIdx.x * 4 + wave;
    const float* xrow = x + (size_t)token * DIM;
    float acc[NEXP];
#pragma unroll
    for (int e = 0; e < NEXP; ++e) acc[e] = 0.f;
#pragma unroll
    for (int i = 0; i < DIM / 64; ++i) {
        const int k = i * 64 + lane;
        const float xv = xrow[k];
#pragma unroll
        for (int e = 0; e < NEXP; ++e) acc[e] += xv * wr[e * DIM + k];
    }
#pragma unroll
    for (int off = 32; off > 0; off >>= 1) {
#pragma unroll
        for (int e = 0; e < NEXP; ++e) acc[e] += __shfl_xor(acc[e], off);
    }
    if (lane == 0) {
        float c0 = -1e30f; int b0 = 0;
#pragma unroll
        for (int e = 0; e < NEXP; ++e) if (acc[e] > c0) { c0 = acc[e]; b0 = e; }
        float c1 = -1e30f; int b1 = 0;
#pragma unroll
        for (int e = 0; e < NEXP; ++e) if (e != b0 && acc[e] > c1) { c1 = acc[e]; b1 = e; }
        slot_ids[token * 2 + 0] = b0;
        slot_ids[token * 2 + 1] = b1;
        const float w0 = 1.f / (1.f + expf(c1 - c0));
        slot_w[token * 2 + 0] = w0;
        slot_w[token * 2 + 1] = 1.f - w0;
        atomicAdd(&counts[b0], 1);
        atomicAdd(&counts[b1], 1);
    }
}

// ---------------- scheduler ----------------
__global__ __launch_bounds__(512) void sched_kernel(const int* __restrict__ counts,
        int* __restrict__ ntiles, int* __restrict__ tile_e, int* __restrict__ tile_m0,
        int* __restrict__ tile_mend, const int* __restrict__ slot_ids,
        int* __restrict__ slot_of_pos, int* __restrict__ pos_of_slot) {
    __shared__ int offs[NEXP];
    if (threadIdx.x == 0) {
        int o = 0, nt = 0;
        for (int e = 0; e < NEXP; ++e) {
            offs[e] = o;
            const int c = counts[e];
            for (int m = 0; m < c; m += BM) {
                tile_e[nt] = e; tile_m0[nt] = o + m; tile_mend[nt] = o + c; ++nt;
            }
            o += c;
        }
        *ntiles = nt;
    }
    __syncthreads();
    const int e = threadIdx.x >> 6;
    const int lane = threadIdx.x & 63;
    int base = offs[e];
    for (int ch = 0; ch < NSLOT / 64; ++ch) {
        const int i = ch * 64 + lane;
        const int id = slot_ids[i];
        const unsigned long long m = __ballot(id == e);
        if (id == e) {
            const int rank = __popcll(m & ((1ull << lane) - 1ull));
            slot_of_pos[base + rank] = i;
            pos_of_slot[i] = base + rank;
        }
        base += __popcll(m);
    }
}

// ---------------- gather ----------------
__global__ __launch_bounds__(256) void gather_kernel(const float* __restrict__ x,
        const int* __restrict__ slot_of_pos, bf16_t* __restrict__ xs) {
    const int row = blockIdx.x;
    const int t = threadIdx.x;
    const int tok = slot_of_pos[row] >> 1;
    const float4 v = *(const float4*)(x + (size_t)tok * DIM + t * 4);
    bf16x4 o;
    o.x = (bf16_t)v.x; o.y = (bf16_t)v.y; o.z = (bf16_t)v.z; o.w = (bf16_t)v.w;
    *(bf16x4*)(xs + (size_t)row * DIM + t * 4) = o;
}

// ---------------- swiglu ----------------
__global__ __launch_bounds__(256) void swiglu_kernel(const bf16_t* __restrict__ hraw,
        bf16_t* __restrict__ h1) {
    const int row = blockIdx.x;
    const int col = blockIdx.y * 256 + threadIdx.x;
    if (col >= H1_LD) return;
    float o = 0.f;
    if (col < HIDDEN) {
        const float a = (float)hraw[(size_t)row * HRAW_LD + col];
        const float g = (float)hraw[(size_t)row * HRAW_LD + col + HIDDEN];
        o = a * (g / (1.f + expf(-g)));
    }
    h1[(size_t)row * H1_LD + col] = (bf16_t)o;
}

// ---------------- combine ----------------
__global__ __launch_bounds__(256) void combine_kernel(const bf16_t* __restrict__ logits,
        const int* __restrict__ pos_of_slot, const float* __restrict__ slot_w,
        float* __restrict__ out) {
    const int t = blockIdx.x;
    const int v0 = (blockIdx.y * 256 + threadIdx.x) * 8;
    const int p0 = pos_of_slot[2 * t], p1 = pos_of_slot[2 * t + 1];
    const float w0 = slot_w[2 * t], w1 = slot_w[2 * t + 1];
    const bf16x8 a = *(const bf16x8*)(logits + (size_t)p0 * VOCAB + v0);
    const bf16x8 b = *(const bf16x8*)(logits + (size_t)p1 * VOCAB + v0);
    float o[8];
#pragma unroll
    for (int i = 0; i < 8; ++i) o[i] = w0 * (float)a[i] + w1 * (float)b[i];
    *(float4*)(out + (size_t)t * VOCAB + v0)     = make_float4(o[0], o[1], o[2], o[3]);
    *(float4*)(out + (size_t)t * VOCAB + v0 + 4) = make_float4(o[4], o[5], o[6], o[7]);
}

// ================= gemm_pk: 1-barrier/step deep-prefetch pipeline ======================
// BM=256 BN=256 BK=32, K=1024, 1024 thr = 16 waves (4M x 4N), per-wave 64x64, acc[4][4].
// Packed conflict-free LDS (R10): logical [256][32] bf16 -> phys [128][64];
//   phys[p][u] = logical(row = p + 128*(ou>=4), kunit = ou&3), ou = u ^ (p&7).
// A: LDS triple-buffer via global_load_lds (stage t+2); B: 4 named reg sets (load t+4),
// cvt->bf16 swizzled ds_write into LDS double-buffer (write t+1).
// Per step: vmcnt(5) drains exactly {B(t+1)x2, A(t)} -> B budget 3 steps, A 2 steps.
// ONE barrier per step; lgkmcnt(0) before it publishes prev ds_writes + frees regs.
// EPI 0: store bf16 C (ldc)   EPI 2: scaled atomicAdd into out
template <int EPI, bool SWZ>
__global__ __launch_bounds__(1024, 4) void gemm_pk(
        const bf16_t* __restrict__ A,
        const float* __restrict__ B, int N,
        bf16_t* __restrict__ C, int ldc,
        const int* __restrict__ slot_of_pos,
        const float* __restrict__ slot_w,
        float* __restrict__ outp,
        const int* __restrict__ tile_e,
        const int* __restrict__ tile_m0,
        const int* __restrict__ tile_mend,
        const int* __restrict__ ntiles) {
    if (blockIdx.y >= (unsigned)*ntiles) return;
    constexpr int K = 1024, KT = 32;
    int bx = blockIdx.x;
    if constexpr (SWZ) bx = (bx & 7) * (gridDim.x >> 3) + (bx >> 3);
    const int e = tile_e[blockIdx.y];
    const int m0 = tile_m0[blockIdx.y];
    const int mend = tile_mend[blockIdx.y];
    const int n0 = bx * 256;
    const float* __restrict__ Bexp = B + (size_t)e * N * K;

    __shared__ bf16_t sA[3][128][64];   // 48 KB, packed 128B rows
    __shared__ bf16_t sB[2][128][64];   // 32 KB

    const int tid = threadIdx.x;
    const int lane = tid & 63;
    const int wave = tid >> 6;
    const int wr = wave >> 2;            // 0..3 -> M strip wr*64
    const int wc = wave & 3;             // 0..3 -> N strip wc*64
    const int fr = lane & 15;
    const int fq = lane >> 4;

    // A-DMA per-lane source map (window = phys rows wave*8 .. wave*8+7)
    const int a_ou = (lane & 7) ^ (lane >> 3);
    const int a_r  = wave * 8 + (lane >> 3) + ((a_ou & 4) << 5);
    const int a_k16 = (a_ou & 3) * 8;

    // B staging per-thread map: phys slot (bp, bu) -> logical (row, kunit)
    const int bp  = tid >> 3;
    const int bu  = tid & 7;
    const int bou = bu ^ (bp & 7);
    const int b_row = bp + ((bou & 4) << 5);
    const int b_k   = (bou & 3) * 8;
    const float* bsrc = Bexp + (size_t)min(n0 + b_row, N - 1) * K + b_k;

    f32x4 acc[4][4] = {};

    auto stageA = [&](int buf, int kt) {      // 1 x 1KB DMA per wave
        const int k0 = min(kt, KT - 1) * 32;
        const int gr = min(m0 + a_r, NSLOT - 1);
        gload_lds16(A + (size_t)gr * K + k0 + a_k16, &sA[buf][wave * 8][0]);
    };
    auto loadB = [&](int kt, f32x4& v0, f32x4& v1) {   // 2 f32x4 per thread
        const int k0 = min(kt, KT - 1) * 32;
        v0 = *(const f32x4*)(bsrc + k0);
        v1 = *(const f32x4*)(bsrc + k0 + 4);
    };
    auto writeB = [&](int buf, const f32x4& v0, const f32x4& v1) {  // 1 ds_write_b128
        bf16x8 t;
        t[0] = (bf16_t)v0[0]; t[1] = (bf16_t)v0[1];
        t[2] = (bf16_t)v0[2]; t[3] = (bf16_t)v0[3];
        t[4] = (bf16_t)v1[0]; t[5] = (bf16_t)v1[1];
        t[6] = (bf16_t)v1[2]; t[7] = (bf16_t)v1[3];
        *(bf16x8*)&sB[buf][bp][bu * 8] = t;
    };
    auto compute = [&](int bufA, int bufB) {
        bf16x8 bb[4];
#pragma unroll
        for (int ni = 0; ni < 4; ++ni) {
            const int r = wc * 64 + ni * 16 + fr;
            const int p = r & 127;
            const int u = (((r >> 7) << 2) + fq) ^ (fr & 7);
            bb[ni] = *(const bf16x8*)&sB[bufB][p][u * 8];
        }
        __builtin_amdgcn_s_setprio(1);
#pragma unroll
        for (int mi = 0; mi < 4; ++mi) {
            const int r = wr * 64 + mi * 16 + fr;
            const int p = r & 127;
            const int u = (((r >> 7) << 2) + fq) ^ (fr & 7);
            const bf16x8 af = *(const bf16x8*)&sA[bufA][p][u * 8];
#pragma unroll
            for (int ni = 0; ni < 4; ++ni)
                acc[mi][ni] = __builtin_amdgcn_mfma_f32_16x16x32_bf16(
                        af, bb[ni], acc[mi][ni], 0, 0, 0);
        }
        __builtin_amdgcn_s_setprio(0);
    };

    // one pipeline step; reg indices static per call site (rule #20)
    auto step = [&](int t, f32x4& Wa, f32x4& Wb,   // reg set (t+1)%4: write to LDS
                    f32x4& La, f32x4& Lb) {        // reg set t%4: reload with B(t+4)
        asm volatile("s_waitcnt vmcnt(5)" ::: "memory");   // drains {B(t+1)x2, A(t)}
        asm volatile("s_waitcnt lgkmcnt(0)" ::: "memory"); // prev ds_writes/reads done
        __builtin_amdgcn_s_barrier();
        asm volatile("" ::: "memory");
        stageA((t + 2) % 3, t + 2);                // before loadB: decouple A from B drain
        loadB(t + 4, La, Lb);
        writeB((t + 1) & 1, Wa, Wb);
        compute(t % 3, t & 1);
        asm volatile("" ::: "memory");
    };

    f32x4 R0a, R0b, R1a, R1b, R2a, R2b, R3a, R3b;
    // prologue — queue after: [B0(2), B1(2), A0, B2(2), A1, B3(2)] = 10
    loadB(0, R0a, R0b);
    loadB(1, R1a, R1b);
    stageA(0, 0);
    loadB(2, R2a, R2b);
    stageA(1, 1);
    loadB(3, R3a, R3b);
    asm volatile("s_waitcnt vmcnt(8)" ::: "memory");   // drain B0
    writeB(0, R0a, R0b);
    // entering loop, queue = [B1(2), A0, B2(2), A1, B3(2)] = 8 -> step(0)'s vmcnt(5) ok

    for (int t = 0; t < KT; t += 4) {
        step(t + 0, R1a, R1b, R0a, R0b);
        step(t + 1, R2a, R2b, R1a, R1b);
        step(t + 2, R3a, R3b, R2a, R2b);
        step(t + 3, R0a, R0b, R3a, R3b);
    }

    // epilogue: C/D layout col = lane&15, row = (lane>>4)*4 + reg
#pragma unroll
    for (int mi = 0; mi < 4; ++mi) {
#pragma unroll
        for (int reg = 0; reg < 4; ++reg) {
            const int r = m0 + wr * 64 + mi * 16 + fq * 4 + reg;
            if (r >= mend) continue;
            int tok = 0; float wgt = 0.f;
            if constexpr (EPI == 2) {
                const int slot = slot_of_pos[r];
                tok = slot >> 1;
                wgt = slot_w[slot];
            }
#pragma unroll
            for (int ni = 0; ni < 4; ++ni) {
                const int c = n0 + wc * 64 + ni * 16 + fr;
                if (c >= N) continue;
                float v = acc[mi][ni][reg];
                if constexpr (EPI == 0) {
                    C[(size_t)r * ldc + c] = (bf16_t)v;
                } else {
                    unsafeAtomicAdd(&outp[(size_t)tok * VOCAB + c], v * wgt);
                }
            }
        }
    }
}

// ================= gemm_mid (R8 structure, down-GEMM K=2730, BN=64) =====================
template <int EPI, int BN, bool SWZ>
__global__ __launch_bounds__(1024, 4) void gemm_mid(
        const bf16_t* __restrict__ A, int lda,
        const float* __restrict__ B, int N, int K, int KT, long bLast,
        bf16_t* __restrict__ C, int ldc,
        const bf16_t* __restrict__ skip,
        const int* __restrict__ tile_e,
        const int* __restrict__ tile_m0,
        const int* __restrict__ tile_mend,
        const int* __restrict__ ntiles) {
    if (blockIdx.y >= (unsigned)*ntiles) return;
    int bx = blockIdx.x;
    if constexpr (SWZ) bx = (bx & 7) * (gridDim.x >> 3) + (bx >> 3);
    const int e = tile_e[blockIdx.y];
    const int m0 = tile_m0[blockIdx.y];
    const int mend = tile_mend[blockIdx.y];
    const int n0 = bx * BN;

    constexpr int NI = BN / 64;

    __shared__ bf16_t sA[2][BM][32];
    __shared__ bf16_t sB[2][BN][32];

    const int tid = threadIdx.x;
    const int lane = tid & 63;
    const int wave = tid >> 6;
    const int wr = wave >> 2;
    const int wc = wave & 3;
    const int fr = lane & 15;
    const int fq = lane >> 4;

    f32x4 acc[4][NI] = {};

    auto stageA = [&](int buf, int kt) {
        const int k0 = min(kt, KT - 1) * 32;
        const int rb = wave * 16;
        const int r = rb + (lane >> 2);
        const int gr = min(m0 + r, NSLOT - 1);
        const int c16 = (lane & 3) ^ swzm(r);
        gload_lds16(A + (size_t)gr * lda + k0 + c16 * 8, &sA[buf][rb][0]);
    };
    auto loadB = [&](int kt, float2& vc) {
        const int k0 = min(kt, KT - 1) * 32;
        long fl = (long)e * N * K + (long)(n0 + wave * 4 + (lane >> 4)) * K
                  + k0 + (lane & 15) * 2;
        if (fl > bLast) fl = bLast;
        vc = *(const float2*)(B + fl);
    };
    auto writeB = [&](int buf, const float2& vc) {
        const int r = wave * 4 + (lane >> 4);
        bf16x2 t; t.x = (bf16_t)vc.x; t.y = (bf16_t)vc.y;
        const int q = lane & 15;
        char* p = (char*)&sB[buf][r][0] + (((q >> 2) ^ swzm(r)) * 16) + (q & 3) * 4;
        *(bf16x2*)p = t;
    };
    auto compute = [&](int buf) {
        bf16x8 af[4], bb[NI];
#pragma unroll
        for (int mi = 0; mi < 4; ++mi) {
            const int r = wr * 64 + mi * 16 + fr;
            af[mi] = *(const bf16x8*)&sA[buf][r][(fq ^ swzm(r)) * 8];
        }
#pragma unroll
        for (int ni = 0; ni < NI; ++ni) {
            const int r = wc * (BN / 4) + ni * 16 + fr;
            bb[ni] = *(const bf16x8*)&sB[buf][r][(fq ^ swzm(r)) * 8];
        }
        __builtin_amdgcn_s_setprio(1);
#pragma unroll
        for (int ni = 0; ni < NI; ++ni)
#pragma unroll
            for (int mi = 0; mi < 4; ++mi)
                acc[mi][ni] = __builtin_amdgcn_mfma_f32_16x16x32_bf16(
                        af[mi], bb[ni], acc[mi][ni], 0, 0, 0);
        __builtin_amdgcn_s_setprio(0);
    };

    float2 Pc, Qc;
    loadB(0, Pc);
    stageA(0, 0);
    loadB(1, Qc);
    asm volatile("s_waitcnt vmcnt(2)" ::: "memory");
    writeB(0, Pc);
    asm volatile("s_waitcnt lgkmcnt(0)" ::: "memory");
    stageA(1, 1);

    for (int kt = 0; kt < KT; kt += 2) {
        loadB(kt + 2, Pc);
        asm volatile("s_waitcnt vmcnt(2)" ::: "memory");
        __builtin_amdgcn_s_barrier();
        asm volatile("" ::: "memory");
        writeB(1, Qc);
        compute(0);
        asm volatile("s_waitcnt lgkmcnt(0)" ::: "memory");
        __builtin_amdgcn_s_barrier();
        asm volatile("" ::: "memory");
        stageA(0, kt + 2);
        loadB(kt + 3, Qc);
        asm volatile("s_waitcnt vmcnt(2)" ::: "memory");
        __builtin_amdgcn_s_barrier();
        asm volatile("" ::: "memory");
        writeB(0, Pc);
        compute(1);
        asm volatile("s_waitcnt lgkmcnt(0)" ::: "memory");
        __builtin_amdgcn_s_barrier();
        asm volatile("" ::: "memory");
        stageA(1, kt + 3);
    }

#pragma unroll
    for (int mi = 0; mi < 4; ++mi) {
#pragma unroll
        for (int reg = 0; reg < 4; ++reg) {
            const int r = m0 + wr * 64 + mi * 16 + fq * 4 + reg;
            if (r >= mend) continue;
#pragma unroll
            for (int ni = 0; ni < NI; ++ni) {
                const int c = n0 + wc * (BN / 4) + ni * 16 + fr;
                if (c >= N) continue;
                float v = acc[mi][ni][reg];
                if constexpr (EPI == 1) v += (float)skip[(size_t)r * DIM + c];
                C[(size_t)r * ldc + c] = (bf16_t)v;
            }
        }
    }
}

extern "C" void kernel_launch(void* const* d_in, const int* in_sizes, int n_in,
                              void* d_out, int out_size, void* d_ws, size_t ws_size,
                              hipStream_t stream) {
    const float* x        = (const float*)d_in[0];
    const float* w_router = (const float*)d_in[1];
    const float* w_up     = (const float*)d_in[2];
    const float* w_down   = (const float*)d_in[3];
    const float* w_proj   = (const float*)d_in[4];
    float* out = (float*)d_out;
    char* ws = (char*)d_ws;

    int*    counts      = (int*)(ws + WS_COUNTS);
    int*    ntiles      = (int*)(ws + WS_NTILES);
    int*    tile_e      = (int*)(ws + WS_TILE_E);
    int*    tile_m0     = (int*)(ws + WS_TILE_M0);
    int*    tile_mend   = (int*)(ws + WS_TILE_MEND);
    int*    slot_ids    = (int*)(ws + WS_SLOT_IDS);
    float*  slot_w      = (float*)(ws + WS_SLOT_W);
    int*    slot_of_pos = (int*)(ws + WS_SLOT_OF_POS);
    int*    pos_of_slot = (int*)(ws + WS_POS_OF_SLOT);
    bf16_t* x_sorted    = (bf16_t*)(ws + WS_XSORTED);
    bf16_t* h2          = (bf16_t*)(ws + WS_H2);
    bf16_t* h1          = (bf16_t*)(ws + WS_H1);
    bf16_t* h_raw       = (bf16_t*)(ws + WS_HRAW);
    bf16_t* logits      = (bf16_t*)(ws + WS_LOGITS);

    const bool bigws = ws_size >= WS_NEED_BIG;

    hipMemsetAsync(d_ws, 0, 1024, stream);

    router_kernel<<<NTOK / 4, 256, 0, stream>>>(x, w_router, slot_ids, slot_w, counts);
    sched_kernel<<<1, 512, 0, stream>>>(counts, ntiles, tile_e, tile_m0, tile_mend,
                                        slot_ids, slot_of_pos, pos_of_slot);
    gather_kernel<<<NSLOT, 256, 0, stream>>>(x, slot_of_pos, x_sorted);

    // up: BN=256 (22 n-blocks, not /8 -> no swizzle)
    gemm_pk<0, false><<<dim3((UPOUT + 255) / 256, MAXTILES), 1024, 0, stream>>>(
        x_sorted, w_up, UPOUT, h_raw, HRAW_LD,
        nullptr, nullptr, nullptr, tile_e, tile_m0, tile_mend, ntiles);

    swiglu_kernel<<<dim3(NSLOT, (H1_LD + 255) / 256), 256, 0, stream>>>(h_raw, h1);

    // down: K=2730, BN=64, grid.x=16 (/8 -> swizzle)
    gemm_mid<1, 64, true><<<dim3(DIM / 64, MAXTILES), 1024, 0, stream>>>(
        h1, H1_LD, w_down, DIM, HIDDEN, (HIDDEN + 31) / 32,
        (long)NEXP * DIM * HIDDEN - 2,
        h2, DIM, x_sorted, tile_e, tile_m0, tile_mend, ntiles);

    if (bigws) {
        gemm_pk<0, true><<<dim3(VOCAB / 256, MAXTILES), 1024, 0, stream>>>(
            h2, w_proj, VOCAB, logits, VOCAB,
            nullptr, nullptr, nullptr, tile_e, tile_m0, tile_mend, ntiles);
        combine_kernel<<<dim3(NTOK, VOCAB / (256 * 8)), 256, 0, stream>>>(
            logits, pos_of_slot, slot_w, out);
    } else {
        hipMemsetAsync(d_out, 0, (size_t)out_size * sizeof(float), stream);
        gemm_pk<2, true><<<dim3(VOCAB / 256, MAXTILES), 1024, 0, stream>>>(
            h2, w_proj, VOCAB, nullptr, 0,
            slot_of_pos, slot_w, out, tile_e, tile_m0, tile_mend, ntiles);
    }
}

// Round 12
// 642.345 us; speedup vs baseline: 1.0793x; 1.0793x over previous
//
#include <hip/hip_runtime.h>
#include <hip/hip_bf16.h>

typedef __bf16 bf16_t;
typedef __bf16 bf16x2 __attribute__((ext_vector_type(2)));
typedef __bf16 bf16x4 __attribute__((ext_vector_type(4)));
typedef __bf16 bf16x8 __attribute__((ext_vector_type(8)));
typedef float f32x4 __attribute__((ext_vector_type(4)));

#define DIM     1024
#define NEXP    8
#define VOCAB   16384
#define HIDDEN  2730
#define UPOUT   5460
#define NTOK    2048
#define NSLOT   4096
#define HRAW_LD 5472
#define H1_LD   2752
#define BM      256
#define MAXTILES 24

// ws layout (offsets in bytes) — verified slack (R8)
#define WS_COUNTS      0
#define WS_NTILES      64
#define WS_TILE_E      128
#define WS_TILE_M0     256
#define WS_TILE_MEND   384
#define WS_SLOT_IDS    1024
#define WS_SLOT_W      20480
#define WS_SLOT_OF_POS 40960
#define WS_POS_OF_SLOT 61440
#define WS_XSORTED     131072
#define WS_H2          8519680
#define WS_H1          16908288
#define WS_HRAW        39452672
#define WS_LOGITS      16908288ull /* overlays h1+h_raw (dead by proj time) */
#define WS_NEED_BIG    (WS_LOGITS + (size_t)NSLOT * VOCAB * 2)

__device__ __forceinline__ void gload_lds16(const void* g, void* l) {
    __builtin_amdgcn_global_load_lds((const __attribute__((address_space(1))) void*)g,
                                     (__attribute__((address_space(3))) void*)l, 16, 0, 0);
}
__device__ __forceinline__ int swzm(int r) { return (r ^ (r >> 2)) & 3; }

// ---------------- router ----------------
__global__ __launch_bounds__(256) void router_kernel(const float* __restrict__ x,
        const float* __restrict__ wr, int* __restrict__ slot_ids,
        float* __restrict__ slot_w, int* __restrict__ counts) {
    const int lane = threadIdx.x & 63;
    const int wave = threadIdx.x >> 6;
    const int token = blockIdx.x * 4 + wave;
    const float* xrow = x + (size_t)token * DIM;
    float acc[NEXP];
#pragma unroll
    for (int e = 0; e < NEXP; ++e) acc[e] = 0.f;
#pragma unroll
    for (int i = 0; i < DIM / 64; ++i) {
        const int k = i * 64 + lane;
        const float xv = xrow[k];
#pragma unroll
        for (int e = 0; e < NEXP; ++e) acc[e] += xv * wr[e * DIM + k];
    }
#pragma unroll
    for (int off = 32; off > 0; off >>= 1) {
#pragma unroll
        for (int e = 0; e < NEXP; ++e) acc[e] += __shfl_xor(acc[e], off);
    }
    if (lane == 0) {
        float c0 = -1e30f; int b0 = 0;
#pragma unroll
        for (int e = 0; e < NEXP; ++e) if (acc[e] > c0) { c0 = acc[e]; b0 = e; }
        float c1 = -1e30f; int b1 = 0;
#pragma unroll
        for (int e = 0; e < NEXP; ++e) if (e != b0 && acc[e] > c1) { c1 = acc[e]; b1 = e; }
        slot_ids[token * 2 + 0] = b0;
        slot_ids[token * 2 + 1] = b1;
        const float w0 = 1.f / (1.f + expf(c1 - c0));
        slot_w[token * 2 + 0] = w0;
        slot_w[token * 2 + 1] = 1.f - w0;
        atomicAdd(&counts[b0], 1);
        atomicAdd(&counts[b1], 1);
    }
}

// ---------------- scheduler ----------------
__global__ __launch_bounds__(512) void sched_kernel(const int* __restrict__ counts,
        int* __restrict__ ntiles, int* __restrict__ tile_e, int* __restrict__ tile_m0,
        int* __restrict__ tile_mend, const int* __restrict__ slot_ids,
        int* __restrict__ slot_of_pos, int* __restrict__ pos_of_slot) {
    __shared__ int offs[NEXP];
    if (threadIdx.x == 0) {
        int o = 0, nt = 0;
        for (int e = 0; e < NEXP; ++e) {
            offs[e] = o;
            const int c = counts[e];
            for (int m = 0; m < c; m += BM) {
                tile_e[nt] = e; tile_m0[nt] = o + m; tile_mend[nt] = o + c; ++nt;
            }
            o += c;
        }
        *ntiles = nt;
    }
    __syncthreads();
    const int e = threadIdx.x >> 6;
    const int lane = threadIdx.x & 63;
    int base = offs[e];
    for (int ch = 0; ch < NSLOT / 64; ++ch) {
        const int i = ch * 64 + lane;
        const int id = slot_ids[i];
        const unsigned long long m = __ballot(id == e);
        if (id == e) {
            const int rank = __popcll(m & ((1ull << lane) - 1ull));
            slot_of_pos[base + rank] = i;
            pos_of_slot[i] = base + rank;
        }
        base += __popcll(m);
    }
}

// ---------------- gather ----------------
__global__ __launch_bounds__(256) void gather_kernel(const float* __restrict__ x,
        const int* __restrict__ slot_of_pos, bf16_t* __restrict__ xs) {
    const int row = blockIdx.x;
    const int t = threadIdx.x;
    const int tok = slot_of_pos[row] >> 1;
    const float4 v = *(const float4*)(x + (size_t)tok * DIM + t * 4);
    bf16x4 o;
    o.x = (bf16_t)v.x; o.y = (bf16_t)v.y; o.z = (bf16_t)v.z; o.w = (bf16_t)v.w;
    *(bf16x4*)(xs + (size_t)row * DIM + t * 4) = o;
}

// ---------------- swiglu ----------------
__global__ __launch_bounds__(256) void swiglu_kernel(const bf16_t* __restrict__ hraw,
        bf16_t* __restrict__ h1) {
    const int row = blockIdx.x;
    const int col = blockIdx.y * 256 + threadIdx.x;
    if (col >= H1_LD) return;
    float o = 0.f;
    if (col < HIDDEN) {
        const float a = (float)hraw[(size_t)row * HRAW_LD + col];
        const float g = (float)hraw[(size_t)row * HRAW_LD + col + HIDDEN];
        o = a * (g / (1.f + expf(-g)));
    }
    h1[(size_t)row * H1_LD + col] = (bf16_t)o;
}

// ---------------- combine ----------------
__global__ __launch_bounds__(256) void combine_kernel(const bf16_t* __restrict__ logits,
        const int* __restrict__ pos_of_slot, const float* __restrict__ slot_w,
        float* __restrict__ out) {
    const int t = blockIdx.x;
    const int v0 = (blockIdx.y * 256 + threadIdx.x) * 8;
    const int p0 = pos_of_slot[2 * t], p1 = pos_of_slot[2 * t + 1];
    const float w0 = slot_w[2 * t], w1 = slot_w[2 * t + 1];
    const bf16x8 a = *(const bf16x8*)(logits + (size_t)p0 * VOCAB + v0);
    const bf16x8 b = *(const bf16x8*)(logits + (size_t)p1 * VOCAB + v0);
    float o[8];
#pragma unroll
    for (int i = 0; i < 8; ++i) o[i] = w0 * (float)a[i] + w1 * (float)b[i];
    *(float4*)(out + (size_t)t * VOCAB + v0)     = make_float4(o[0], o[1], o[2], o[3]);
    *(float4*)(out + (size_t)t * VOCAB + v0 + 4) = make_float4(o[4], o[5], o[6], o[7]);
}

// ================= gemm_d2: R8 champion + depth-2 B prefetch (4 named reg sets) ========
// BM=256 BN=256 BK=32, K=1024, 1024 thr = 16 waves (4M x 4N), per-wave 64x64, acc[4][4].
// LDS 64 KB (2 blocks/CU), 2 barriers/step — identical to R8. Only change:
// loadB(t+3) issued at step t (2-step latency budget), vmcnt(5) drains {B(t+1)x2, A(t)}.
// EPI 0: store bf16 C (ldc)   EPI 2: scaled atomicAdd into out
template <int EPI, bool SWZ>
__global__ __launch_bounds__(1024, 4) void gemm_d2(
        const bf16_t* __restrict__ A,
        const float* __restrict__ B, int N,
        bf16_t* __restrict__ C, int ldc,
        const int* __restrict__ slot_of_pos,
        const float* __restrict__ slot_w,
        float* __restrict__ outp,
        const int* __restrict__ tile_e,
        const int* __restrict__ tile_m0,
        const int* __restrict__ tile_mend,
        const int* __restrict__ ntiles) {
    if (blockIdx.y >= (unsigned)*ntiles) return;
    constexpr int K = 1024, KT = 32;
    int bx = blockIdx.x;
    if constexpr (SWZ) bx = (bx & 7) * (gridDim.x >> 3) + (bx >> 3);
    const int e = tile_e[blockIdx.y];
    const int m0 = tile_m0[blockIdx.y];
    const int mend = tile_mend[blockIdx.y];
    const int n0 = bx * 256;
    const float* __restrict__ Bexp = B + (size_t)e * N * K;

    __shared__ bf16_t sA[2][256][32];   // 16 KB/buf, unit16 ^= swzm(row)
    __shared__ bf16_t sB[2][256][32];   // 16 KB/buf

    const int tid = threadIdx.x;
    const int lane = tid & 63;
    const int wave = tid >> 6;
    const int wr = wave >> 2;            // 0..3 -> M strip wr*64
    const int wc = wave & 3;             // 0..3 -> N strip wc*64
    const int fr = lane & 15;
    const int fq = lane >> 4;

    f32x4 acc[4][4] = {};

    auto stageA = [&](int buf, int kt) {      // 1 x 1KB DMA per wave
        const int k0 = min(kt, KT - 1) * 32;
        const int rb = wave * 16;
        const int r = rb + (lane >> 2);
        const int gr = min(m0 + r, NSLOT - 1);
        const int c16 = (lane & 3) ^ swzm(r);
        gload_lds16(A + (size_t)gr * K + k0 + c16 * 8, &sA[buf][rb][0]);
    };
    auto loadB = [&](int kt, f32x4* va) {     // 2 x f32x4 per thread (rows, +128 rows)
        const int k0 = min(kt, KT - 1) * 32;
#pragma unroll
        for (int nb = 0; nb < 2; ++nb) {
            const int gr = min(n0 + nb * 128 + wave * 8 + (lane >> 3), N - 1);
            va[nb] = *(const f32x4*)(Bexp + (size_t)gr * K + k0 + (lane & 7) * 4);
        }
    };
    auto writeB = [&](int buf, const f32x4* va) {
#pragma unroll
        for (int nb = 0; nb < 2; ++nb) {
            const int r = nb * 128 + wave * 8 + (lane >> 3);
            bf16x4 t;
            t.x = (bf16_t)va[nb].x; t.y = (bf16_t)va[nb].y;
            t.z = (bf16_t)va[nb].z; t.w = (bf16_t)va[nb].w;
            char* p = (char*)&sB[buf][r][0]
                    + ((((lane & 7) >> 1) ^ swzm(r)) * 16) + (lane & 1) * 8;
            *(bf16x4*)p = t;
        }
    };
    auto compute = [&](int buf) {
        bf16x8 bb[4];
#pragma unroll
        for (int ni = 0; ni < 4; ++ni) {
            const int r = wc * 64 + ni * 16 + fr;
            bb[ni] = *(const bf16x8*)&sB[buf][r][(fq ^ swzm(r)) * 8];
        }
        __builtin_amdgcn_s_setprio(1);
#pragma unroll
        for (int mi = 0; mi < 4; ++mi) {
            const int r = wr * 64 + mi * 16 + fr;
            const bf16x8 af = *(const bf16x8*)&sA[buf][r][(fq ^ swzm(r)) * 8];
#pragma unroll
            for (int ni = 0; ni < 4; ++ni)
                acc[mi][ni] = __builtin_amdgcn_mfma_f32_16x16x32_bf16(
                        af, bb[ni], acc[mi][ni], 0, 0, 0);
        }
        __builtin_amdgcn_s_setprio(0);
    };

    // 4 named B register sets (rule #20): set s holds B(t) with t%4 == s
    f32x4 S0[2], S1[2], S2[2], S3[2];

    // prologue: loadB(0,S0); loadB(1,S1); stageA(0); loadB(2,S2);
    // queue = [B0x2, B1x2, A0, B2x2] = 7 -> vmcnt(5) drains B0
    loadB(0, S0);
    loadB(1, S1);
    stageA(0, 0);
    loadB(2, S2);
    asm volatile("s_waitcnt vmcnt(5)" ::: "memory");
    writeB(0, S0);
    asm volatile("s_waitcnt lgkmcnt(0)" ::: "memory");
    stageA(1, 1);
    // queue entering loop = [B1x2, A0, B2x2, A1] = 6

    // step t: loadB(t+3)->set[(t+3)%4]; vmcnt(5) drains {B(t+1)x2, A(t)};
    //         barrier; writeB(buf (t+1)&1, set[(t+1)%4]); compute(t&1);
    //         lgkmcnt(0); barrier; stageA(buf t&1, t+2).
#define D2_STEP(T, SL, SW)                                          \
    loadB((T) + 3, SL);                                             \
    asm volatile("s_waitcnt vmcnt(5)" ::: "memory");                \
    __builtin_amdgcn_s_barrier();                                   \
    asm volatile("" ::: "memory");                                  \
    writeB(((T) + 1) & 1, SW);                                      \
    compute((T) & 1);                                               \
    asm volatile("s_waitcnt lgkmcnt(0)" ::: "memory");              \
    __builtin_amdgcn_s_barrier();                                   \
    asm volatile("" ::: "memory");                                  \
    stageA((T) & 1, (T) + 2);

    for (int kt = 0; kt < KT; kt += 4) {
        D2_STEP(kt + 0, S3, S1);
        D2_STEP(kt + 1, S0, S2);
        D2_STEP(kt + 2, S1, S3);
        D2_STEP(kt + 3, S2, S0);
    }
#undef D2_STEP

    // epilogue: C/D layout col = lane&15, row = (lane>>4)*4 + reg
#pragma unroll
    for (int mi = 0; mi < 4; ++mi) {
#pragma unroll
        for (int reg = 0; reg < 4; ++reg) {
            const int r = m0 + wr * 64 + mi * 16 + fq * 4 + reg;
            if (r >= mend) continue;
            int tok = 0; float wgt = 0.f;
            if constexpr (EPI == 2) {
                const int slot = slot_of_pos[r];
                tok = slot >> 1;
                wgt = slot_w[slot];
            }
#pragma unroll
            for (int ni = 0; ni < 4; ++ni) {
                const int c = n0 + wc * 64 + ni * 16 + fr;
                if (c >= N) continue;
                float v = acc[mi][ni][reg];
                if constexpr (EPI == 0) {
                    C[(size_t)r * ldc + c] = (bf16_t)v;
                } else {
                    unsafeAtomicAdd(&outp[(size_t)tok * VOCAB + c], v * wgt);
                }
            }
        }
    }
}

// ================= gemm_mid (R8 structure, down-GEMM K=2730, BN=64) =====================
template <int EPI, int BN, bool SWZ>
__global__ __launch_bounds__(1024, 4) void gemm_mid(
        const bf16_t* __restrict__ A, int lda,
        const float* __restrict__ B, int N, int K, int KT, long bLast,
        bf16_t* __restrict__ C, int ldc,
        const bf16_t* __restrict__ skip,
        const int* __restrict__ tile_e,
        const int* __restrict__ tile_m0,
        const int* __restrict__ tile_mend,
        const int* __restrict__ ntiles) {
    if (blockIdx.y >= (unsigned)*ntiles) return;
    int bx = blockIdx.x;
    if constexpr (SWZ) bx = (bx & 7) * (gridDim.x >> 3) + (bx >> 3);
    const int e = tile_e[blockIdx.y];
    const int m0 = tile_m0[blockIdx.y];
    const int mend = tile_mend[blockIdx.y];
    const int n0 = bx * BN;

    constexpr int NI = BN / 64;

    __shared__ bf16_t sA[2][BM][32];
    __shared__ bf16_t sB[2][BN][32];

    const int tid = threadIdx.x;
    const int lane = tid & 63;
    const int wave = tid >> 6;
    const int wr = wave >> 2;
    const int wc = wave & 3;
    const int fr = lane & 15;
    const int fq = lane >> 4;

    f32x4 acc[4][NI] = {};

    auto stageA = [&](int buf, int kt) {
        const int k0 = min(kt, KT - 1) * 32;
        const int rb = wave * 16;
        const int r = rb + (lane >> 2);
        const int gr = min(m0 + r, NSLOT - 1);
        const int c16 = (lane & 3) ^ swzm(r);
        gload_lds16(A + (size_t)gr * lda + k0 + c16 * 8, &sA[buf][rb][0]);
    };
    auto loadB = [&](int kt, float2& vc) {
        const int k0 = min(kt, KT - 1) * 32;
        long fl = (long)e * N * K + (long)(n0 + wave * 4 + (lane >> 4)) * K
                  + k0 + (lane & 15) * 2;
        if (fl > bLast) fl = bLast;
        vc = *(const float2*)(B + fl);
    };
    auto writeB = [&](int buf, const float2& vc) {
        const int r = wave * 4 + (lane >> 4);
        bf16x2 t; t.x = (bf16_t)vc.x; t.y = (bf16_t)vc.y;
        const int q = lane & 15;
        char* p = (char*)&sB[buf][r][0] + (((q >> 2) ^ swzm(r)) * 16) + (q & 3) * 4;
        *(bf16x2*)p = t;
    };
    auto compute = [&](int buf) {
        bf16x8 af[4], bb[NI];
#pragma unroll
        for (int mi = 0; mi < 4; ++mi) {
            const int r = wr * 64 + mi * 16 + fr;
            af[mi] = *(const bf16x8*)&sA[buf][r][(fq ^ swzm(r)) * 8];
        }
#pragma unroll
        for (int ni = 0; ni < NI; ++ni) {
            const int r = wc * (BN / 4) + ni * 16 + fr;
            bb[ni] = *(const bf16x8*)&sB[buf][r][(fq ^ swzm(r)) * 8];
        }
        __builtin_amdgcn_s_setprio(1);
#pragma unroll
        for (int ni = 0; ni < NI; ++ni)
#pragma unroll
            for (int mi = 0; mi < 4; ++mi)
                acc[mi][ni] = __builtin_amdgcn_mfma_f32_16x16x32_bf16(
                        af[mi], bb[ni], acc[mi][ni], 0, 0, 0);
        __builtin_amdgcn_s_setprio(0);
    };

    float2 Pc, Qc;
    loadB(0, Pc);
    stageA(0, 0);
    loadB(1, Qc);
    asm volatile("s_waitcnt vmcnt(2)" ::: "memory");
    writeB(0, Pc);
    asm volatile("s_waitcnt lgkmcnt(0)" ::: "memory");
    stageA(1, 1);

    for (int kt = 0; kt < KT; kt += 2) {
        loadB(kt + 2, Pc);
        asm volatile("s_waitcnt vmcnt(2)" ::: "memory");
        __builtin_amdgcn_s_barrier();
        asm volatile("" ::: "memory");
        writeB(1, Qc);
        compute(0);
        asm volatile("s_waitcnt lgkmcnt(0)" ::: "memory");
        __builtin_amdgcn_s_barrier();
        asm volatile("" ::: "memory");
        stageA(0, kt + 2);
        loadB(kt + 3, Qc);
        asm volatile("s_waitcnt vmcnt(2)" ::: "memory");
        __builtin_amdgcn_s_barrier();
        asm volatile("" ::: "memory");
        writeB(0, Pc);
        compute(1);
        asm volatile("s_waitcnt lgkmcnt(0)" ::: "memory");
        __builtin_amdgcn_s_barrier();
        asm volatile("" ::: "memory");
        stageA(1, kt + 3);
    }

#pragma unroll
    for (int mi = 0; mi < 4; ++mi) {
#pragma unroll
        for (int reg = 0; reg < 4; ++reg) {
            const int r = m0 + wr * 64 + mi * 16 + fq * 4 + reg;
            if (r >= mend) continue;
#pragma unroll
            for (int ni = 0; ni < NI; ++ni) {
                const int c = n0 + wc * (BN / 4) + ni * 16 + fr;
                if (c >= N) continue;
                float v = acc[mi][ni][reg];
                if constexpr (EPI == 1) v += (float)skip[(size_t)r * DIM + c];
                C[(size_t)r * ldc + c] = (bf16_t)v;
            }
        }
    }
}

extern "C" void kernel_launch(void* const* d_in, const int* in_sizes, int n_in,
                              void* d_out, int out_size, void* d_ws, size_t ws_size,
                              hipStream_t stream) {
    const float* x        = (const float*)d_in[0];
    const float* w_router = (const float*)d_in[1];
    const float* w_up     = (const float*)d_in[2];
    const float* w_down   = (const float*)d_in[3];
    const float* w_proj   = (const float*)d_in[4];
    float* out = (float*)d_out;
    char* ws = (char*)d_ws;

    int*    counts      = (int*)(ws + WS_COUNTS);
    int*    ntiles      = (int*)(ws + WS_NTILES);
    int*    tile_e      = (int*)(ws + WS_TILE_E);
    int*    tile_m0     = (int*)(ws + WS_TILE_M0);
    int*    tile_mend   = (int*)(ws + WS_TILE_MEND);
    int*    slot_ids    = (int*)(ws + WS_SLOT_IDS);
    float*  slot_w      = (float*)(ws + WS_SLOT_W);
    int*    slot_of_pos = (int*)(ws + WS_SLOT_OF_POS);
    int*    pos_of_slot = (int*)(ws + WS_POS_OF_SLOT);
    bf16_t* x_sorted    = (bf16_t*)(ws + WS_XSORTED);
    bf16_t* h2          = (bf16_t*)(ws + WS_H2);
    bf16_t* h1          = (bf16_t*)(ws + WS_H1);
    bf16_t* h_raw       = (bf16_t*)(ws + WS_HRAW);
    bf16_t* logits      = (bf16_t*)(ws + WS_LOGITS);

    const bool bigws = ws_size >= WS_NEED_BIG;

    hipMemsetAsync(d_ws, 0, 1024, stream);

    router_kernel<<<NTOK / 4, 256, 0, stream>>>(x, w_router, slot_ids, slot_w, counts);
    sched_kernel<<<1, 512, 0, stream>>>(counts, ntiles, tile_e, tile_m0, tile_mend,
                                        slot_ids, slot_of_pos, pos_of_slot);
    gather_kernel<<<NSLOT, 256, 0, stream>>>(x, slot_of_pos, x_sorted);

    // up: BN=256 (22 n-blocks, not /8 -> no swizzle)
    gemm_d2<0, false><<<dim3((UPOUT + 255) / 256, MAXTILES), 1024, 0, stream>>>(
        x_sorted, w_up, UPOUT, h_raw, HRAW_LD,
        nullptr, nullptr, nullptr, tile_e, tile_m0, tile_mend, ntiles);

    swiglu_kernel<<<dim3(NSLOT, (H1_LD + 255) / 256), 256, 0, stream>>>(h_raw, h1);

    // down: K=2730, BN=64, grid.x=16 (/8 -> swizzle)
    gemm_mid<1, 64, true><<<dim3(DIM / 64, MAXTILES), 1024, 0, stream>>>(
        h1, H1_LD, w_down, DIM, HIDDEN, (HIDDEN + 31) / 32,
        (long)NEXP * DIM * HIDDEN - 2,
        h2, DIM, x_sorted, tile_e, tile_m0, tile_mend, ntiles);

    if (bigws) {
        gemm_d2<0, true><<<dim3(VOCAB / 256, MAXTILES), 1024, 0, stream>>>(
            h2, w_proj, VOCAB, logits, VOCAB,
            nullptr, nullptr, nullptr, tile_e, tile_m0, tile_mend, ntiles);
        combine_kernel<<<dim3(NTOK, VOCAB / (256 * 8)), 256, 0, stream>>>(
            logits, pos_of_slot, slot_w, out);
    } else {
        hipMemsetAsync(d_out, 0, (size_t)out_size * sizeof(float), stream);
        gemm_d2<2, true><<<dim3(VOCAB / 256, MAXTILES), 1024, 0, stream>>>(
            h2, w_proj, VOCAB, nullptr, 0,
            slot_of_pos, slot_w, out, tile_e, tile_m0, tile_mend, ntiles);
    }
}